// Round 8
// baseline (175.651 us; speedup 1.0000x reference)
//
#include <hip/hip_runtime.h>
#include <math.h>

#define E_TOTAL 32768
#define NUM_NODES 4096
#define SCALE 0.70710678118654752f

typedef __attribute__((ext_vector_type(8))) short bfrag;
typedef __attribute__((ext_vector_type(16))) float facc;

#define MFMA __builtin_amdgcn_mfma_f32_32x32x16_bf16

__device__ inline unsigned short f2bf(float f) {
  unsigned int u = __float_as_uint(f);
  unsigned int r = (u + 0x7FFFu + ((u >> 16) & 1u)) >> 16;
  return (unsigned short)r;
}
__device__ inline float bf2f(unsigned short s) {
  return __uint_as_float(((unsigned int)s) << 16);
}
__device__ inline void cvt8(const float* v, bfrag& hi, bfrag& lo) {
#pragma unroll
  for (int i = 0; i < 8; ++i) {
    unsigned short h = f2bf(v[i]);
    hi[i] = (short)h;
    lo[i] = (short)f2bf(v[i] - bf2f(h));
  }
}

// ---------------------------------------------------------------------------
// Combined prep: blocks 0..95 W_p frags, 96..102 W_q frags, 103..230 offsets
// frag layout per tile: [ks(4)][hl(2)][lane(64)][j(8)] bf16 (8 KB)
//   element = W_p[d][w*512 + c*32 + (lane&31)], d = ks*16 + (lane>>5)*8 + j
// m-split stream placement: slot = wslot[w] + c with
//   wslot = {w0:0, w1:64, w2:16, w3:80, w4:32, w5:48}
// -> pr=0 stream quarters at 0,16,32,48; pr=1 at 64,80,32,48.
// ---------------------------------------------------------------------------
__global__ __launch_bounds__(256) void prep_kernel(
    const float* __restrict__ Wp, const float* __restrict__ Wq,
    const int* __restrict__ index,
    unsigned short* __restrict__ fragWp, unsigned short* __restrict__ fragWq,
    int* __restrict__ offs)
{
  const int b = blockIdx.x, t = threadIdx.x;
  if (b < 96) {
    __shared__ unsigned short lds[4096];
    const int c = b / 6, w = b - c * 6;
    const int colbase = w * 512 + c * 32;
    const int cl = t & 31, dg = t >> 5;
#pragma unroll
    for (int i = 0; i < 8; ++i) {
      const int d = dg * 8 + i;
      const float v = Wp[(size_t)d * 3072 + colbase + cl];
      const unsigned short hi = f2bf(v);
      const unsigned short lo = f2bf(v - bf2f(hi));
      const int ks = d >> 4;
      const int lane = ((d >> 3) & 1) * 32 + cl;
      const int j = d & 7;
      lds[(ks * 2 + 0) * 512 + lane * 8 + j] = hi;
      lds[(ks * 2 + 1) * 512 + lane * 8 + j] = lo;
    }
    __syncthreads();
    const int wslot0 = (w == 0) ? 0 : (w == 1) ? 64 : (w == 2) ? 16
                     : (w == 3) ? 80 : (w == 4) ? 32 : 48;
    unsigned short* dst = fragWp + (size_t)(wslot0 + c) * 4096;
    ((uint4*)dst)[t] = ((const uint4*)lds)[t];
    ((uint4*)dst)[t + 256] = ((const uint4*)lds)[t + 256];
  } else if (b < 103) {
    const int slot = b - 96;
    const int w = (slot == 6) ? 5 : slot;
    const float sgn = (slot == 6) ? -1.f : 1.f;
    for (int tt = t; tt < 512; tt += 256) {
      const int lane = tt >> 3, j = tt & 7;
      const int o = lane & 31, c = (lane >> 5) * 8 + j;
      const float v = sgn * Wq[(size_t)(w * 16 + c) * 32 + o];
      const unsigned short hi = f2bf(v);
      const unsigned short lo = f2bf(v - bf2f(hi));
      fragWq[slot * 1024 + lane * 8 + j] = hi;
      fragWq[slot * 1024 + 512 + lane * 8 + j] = lo;
    }
  } else {
    const int tg = (b - 103) * 256 + t;
    if (tg >= E_TOTAL) return;
    const int cur = index[tg];
    const int prev = (tg == 0) ? -1 : index[tg - 1];
    for (int n = prev + 1; n <= cur; ++n) offs[n] = tg;
    if (tg == E_TOTAL - 1)
      for (int n = cur + 1; n <= NUM_NODES; ++n) offs[n] = E_TOTAL;
  }
}

// ---------------------------------------------------------------------------
// Main: 256 blocks (1/CU), 512 threads = 8 waves = 2 waves/SIMD, 128 edges.
// Wave (pairI, chalf, pr) = (wv>>2, (wv>>1)&1, wv&1):
//   pairI -> 64-edge group; pr -> m-split (R7); chalf -> c-range half.
// Each wave streams 32 tiles (4 w-streams x 8 c) feeding TWO 32-edge MFMA
// column blocks from the same A-frag (2 MB/CU total, vs R0's 3 MB).
// Per-SIMD global return caps at ~6.4 B/cyc (R0/R1/R2/R7 synthesis); R7 at
// 1 wave/SIMD reached only 3.3 -> 2 waves/SIMD restores the cap via TLP.
// ka partial over c-half; z linear in ka -> 4-way zred sum per edge-group.
// ---------------------------------------------------------------------------
__global__ __launch_bounds__(512, 2) void main_kernel(
    const float* __restrict__ x_q, const float* __restrict__ x_k,
    const float* __restrict__ emb,
    const unsigned short* __restrict__ fragWp,
    const unsigned short* __restrict__ fragWq,
    float* __restrict__ z)
{
  __shared__ float xk_t[64][129];   // 33 KB, padded
  __shared__ float zred[8][64][4];  // 8 KB

  const int t = threadIdx.x;
  const int lane = t & 63, wv = t >> 6;
  const int pairI = wv >> 2, chalf = (wv >> 1) & 1, pr = wv & 1;
  const int col = lane & 31, half = lane >> 5;
  const int eb = blockIdx.x * 128;
  const int el0 = pairI * 64 + col;   // edge within block, column-block a
  const int el1 = el0 + 32;           // column-block b
  const int e0 = eb + el0, e1 = eb + el1;

  // stage x_k transposed: thread t -> edge t&127, d-quarter (t>>7)*16
  {
    const int er = t & 127, dq = (t >> 7) * 16;
    const float* src = x_k + (size_t)(eb + er) * 64 + dq;
#pragma unroll
    for (int i = 0; i < 4; ++i) {
      float4 v = *(const float4*)(src + i * 4);
      xk_t[dq + i * 4 + 0][er] = v.x;
      xk_t[dq + i * 4 + 1][er] = v.y;
      xk_t[dq + i * 4 + 2][er] = v.z;
      xk_t[dq + i * 4 + 3][er] = v.w;
    }
  }

  // emb B-fragments hi/lo for BOTH 32-edge column blocks
  bfrag ebh0[4], ebl0[4], ebh1[4], ebl1[4];
#pragma unroll
  for (int ks = 0; ks < 4; ++ks) {
    float tmp[8];
    *(float4*)&tmp[0] = *(const float4*)(emb + (size_t)e0 * 64 + ks * 16 + half * 8);
    *(float4*)&tmp[4] = *(const float4*)(emb + (size_t)e0 * 64 + ks * 16 + half * 8 + 4);
    cvt8(tmp, ebh0[ks], ebl0[ks]);
    *(float4*)&tmp[0] = *(const float4*)(emb + (size_t)e1 * 64 + ks * 16 + half * 8);
    *(float4*)&tmp[4] = *(const float4*)(emb + (size_t)e1 * 64 + ks * 16 + half * 8 + 4);
    cvt8(tmp, ebh1[ks], ebl1[ks]);
  }

  facc kaP0 = {0}, kaQ0 = {0}, kaP1 = {0}, kaQ1 = {0};

  __syncthreads();  // xk_t ready (only barrier before the end)

  // per-parity stream quarters (tile units -> shorts) and scalar rows
  const unsigned short* fb = fragWp + lane * 8;
  const int qb0 = (pr ? 64 : 0) * 4096;   // w1 : w0  -> kaP, scalar x0 (row c)
  const int qb1 = (pr ? 80 : 16) * 4096;  // w3 : w2  -> kaP, scalar x2 (row 32+c)
  const int qb2 = 32 * 4096;              // w4       -> kaQ, x3 : x1
  const int qb3 = 48 * 4096;              // w5       -> kaQ, -x1 : x3
  const int r2 = pr ? 48 : 16;
  const int r3 = pr ? 16 : 48;
  const float sg3 = pr ? -1.f : 1.f;

#define TILE(WB, XA, XB, KA, KB)                                              \
  {                                                                           \
    const unsigned short* wb_ = (WB);                                         \
    bfrag fh[4], fl[4];                                                       \
    _Pragma("unroll")                                                         \
    for (int ks = 0; ks < 4; ++ks) {                                          \
      *(uint4*)&fh[ks] = *(const uint4*)(wb_ + ks * 1024);                    \
      *(uint4*)&fl[ks] = *(const uint4*)(wb_ + ks * 1024 + 512);              \
    }                                                                         \
    facc cc = {0.f}, cd = {0.f};                                              \
    _Pragma("unroll")                                                         \
    for (int ks = 0; ks < 4; ++ks) {                                          \
      cc = MFMA(fh[ks], ebh0[ks], cc, 0, 0, 0);                               \
      cd = MFMA(fh[ks], ebh1[ks], cd, 0, 0, 0);                               \
      cc = MFMA(fh[ks], ebl0[ks], cc, 0, 0, 0);                               \
      cd = MFMA(fh[ks], ebl1[ks], cd, 0, 0, 0);                               \
      cc = MFMA(fl[ks], ebh0[ks], cc, 0, 0, 0);                               \
      cd = MFMA(fl[ks], ebh1[ks], cd, 0, 0, 0);                               \
    }                                                                         \
    _Pragma("unroll")                                                         \
    for (int r = 0; r < 16; ++r) {                                            \
      (KA)[r] = fmaf((XA), cc[r], (KA)[r]);                                   \
      (KB)[r] = fmaf((XB), cd[r], (KB)[r]);                                   \
    }                                                                         \
  }

  for (int c = 0; c < 8; ++c) {
    const int cg = chalf * 8 + c;
    const float xs0a = xk_t[cg][el0],           xs0b = xk_t[cg][el1];
    const float xs1a = xk_t[32 + cg][el0],      xs1b = xk_t[32 + cg][el1];
    const float xs2a = xk_t[r2 + cg][el0],      xs2b = xk_t[r2 + cg][el1];
    const float xs3a = sg3 * xk_t[r3 + cg][el0], xs3b = sg3 * xk_t[r3 + cg][el1];
    TILE(fb + qb0 + cg * 4096, xs0a, xs0b, kaP0, kaP1)
    TILE(fb + qb1 + cg * 4096, xs1a, xs1b, kaP0, kaP1)
    TILE(fb + qb2 + cg * 4096, xs2a, xs2b, kaQ0, kaQ1)
    TILE(fb + qb3 + cg * 4096, xs3a, xs3b, kaQ0, kaQ1)
  }
#undef TILE

  // ---- q via MFMA (C layout matches ka); wave covers its 2 m's for both
  //      edge blocks (qa duplicated across chalf pair); zred sums the 4
  //      partial z contributions per edge-group.
#define QTERM(QA_, A_, S_)                                                    \
  {                                                                           \
    bfrag wh, wl;                                                             \
    *(uint4*)&wh = *(const uint4*)(fragWq + (S_)*1024 + lane * 8);            \
    *(uint4*)&wl = *(const uint4*)(fragWq + (S_)*1024 + 512 + lane * 8);      \
    QA_ = MFMA(wh, xqh[A_], QA_, 0, 0, 0);                                    \
    QA_ = MFMA(wh, xql[A_], QA_, 0, 0, 0);                                    \
    QA_ = MFMA(wl, xqh[A_], QA_, 0, 0, 0);                                    \
  }

#pragma unroll
  for (int blk = 0; blk < 2; ++blk) {
    const int e = blk ? e1 : e0;
    bfrag xqh[4], xql[4];
#pragma unroll
    for (int a = 0; a < 4; ++a) {
      float tmp[8];
      *(float4*)&tmp[0] = *(const float4*)(x_q + (size_t)e * 64 + a * 16 + half * 8);
      *(float4*)&tmp[4] = *(const float4*)(x_q + (size_t)e * 64 + a * 16 + half * 8 + 4);
      cvt8(tmp, xqh[a], xql[a]);
    }
    facc qaP = {0.f}, qaQ = {0.f};
    if (pr == 0) {
      QTERM(qaP, 0, 0) QTERM(qaP, 2, 2)   // m0: Wq0*xq0 + Wq2*xq2
      QTERM(qaQ, 1, 4) QTERM(qaQ, 3, 5)   // m1: Wq4*xq1 + Wq5*xq3
    } else {
      QTERM(qaP, 0, 1) QTERM(qaP, 2, 3)   // m2: Wq1*xq0 + Wq3*xq2
      QTERM(qaQ, 3, 4) QTERM(qaQ, 1, 6)   // m3: Wq4*xq3 - Wq5*xq1 (slot6=-Wq5)
    }
    const facc& kp = blk ? kaP1 : kaP0;
    const facc& kq = blk ? kaQ1 : kaQ0;
    float zp0 = 0.f, zp1 = 0.f, zp2 = 0.f, zp3 = 0.f;
#pragma unroll
    for (int r = 0; r < 16; ++r) {
      const float v = qaP[r] * kp[r] + qaQ[r] * kq[r];
      if (r < 4) zp0 += v;
      else if (r < 8) zp1 += v;
      else if (r < 12) zp2 += v;
      else zp3 += v;
    }
    zp0 += __shfl_xor(zp0, 32);
    zp1 += __shfl_xor(zp1, 32);
    zp2 += __shfl_xor(zp2, 32);
    zp3 += __shfl_xor(zp3, 32);
    if (half == 0) {
      float4 v = {zp0, zp1, zp2, zp3};
      *(float4*)&zred[wv][blk * 32 + col][0] = v;
    }
  }
#undef QTERM

  __syncthreads();
  if (pr == 0 && chalf == 0 && half == 0) {
#pragma unroll
    for (int blk = 0; blk < 2; ++blk) {
      const int idx = blk * 32 + col;
      float4 a = *(const float4*)&zred[wv + 0][idx][0];
      float4 b = *(const float4*)&zred[wv + 1][idx][0];
      float4 cc = *(const float4*)&zred[wv + 2][idx][0];
      float4 d = *(const float4*)&zred[wv + 3][idx][0];
      float4 o = {(a.x + b.x + cc.x + d.x) * SCALE,
                  (a.y + b.y + cc.y + d.y) * SCALE,
                  (a.z + b.z + cc.z + d.z) * SCALE,
                  (a.w + b.w + cc.w + d.w) * SCALE};
      *(float4*)&z[(size_t)(eb + pairI * 64 + idx) * 4] = o;
    }
  }
}

// ---------------------------------------------------------------------------
__global__ __launch_bounds__(256) void softmax_kernel(
    const float* __restrict__ z, const int* __restrict__ offs,
    float* __restrict__ out)
{
  const int node = blockIdx.x * 4 + (threadIdx.x >> 6);
  const int lane = threadIdx.x & 63;
  const int start = offs[node], end = offs[node + 1];
  if (start >= end) return;
  const int h = lane & 3, eo = lane >> 2;
  float m = -INFINITY;
  for (int e = start + eo; e < end; e += 16) m = fmaxf(m, z[(size_t)e * 4 + h]);
#pragma unroll
  for (int s = 4; s < 64; s <<= 1) m = fmaxf(m, __shfl_xor(m, s));
  float sum = 0.f;
  for (int e = start + eo; e < end; e += 16) sum += __expf(z[(size_t)e * 4 + h] - m);
#pragma unroll
  for (int s = 4; s < 64; s <<= 1) sum += __shfl_xor(sum, s);
  const float inv = 1.f / sum;
  for (int e = start + eo; e < end; e += 16)
    out[(size_t)e * 4 + h] = __expf(z[(size_t)e * 4 + h] - m) * inv;
}

extern "C" void kernel_launch(void* const* d_in, const int* in_sizes, int n_in,
                              void* d_out, int out_size, void* d_ws, size_t ws_size,
                              hipStream_t stream) {
  const float* x_q = (const float*)d_in[0];
  const float* x_k = (const float*)d_in[1];
  const float* emb = (const float*)d_in[2];
  const int* index = (const int*)d_in[3];
  const float* W_q = (const float*)d_in[4];
  const float* W_p = (const float*)d_in[5];
  float* out = (float*)d_out;

  char* ws = (char*)d_ws;
  float* z = (float*)ws;                                                    // 524288 B
  int* offs = (int*)(ws + 524288);                                          // 16388 B (pad 32 KB)
  unsigned short* fragWp = (unsigned short*)(ws + 524288 + 32768);          // 786432 B
  unsigned short* fragWq = (unsigned short*)(ws + 524288 + 32768 + 786432); // 14336 B

  prep_kernel<<<231, 256, 0, stream>>>(W_p, W_q, index, fragWp, fragWq, offs);
  main_kernel<<<256, 512, 0, stream>>>(x_q, x_k, emb, fragWp, fragWq, z);
  softmax_kernel<<<1024, 256, 0, stream>>>(z, offs, out);
}